// Round 10
// baseline (208.306 us; speedup 1.0000x reference)
//
#include <hip/hip_runtime.h>

// Depthwise 4x4 FIR blur, pad (2,2)/(2,2), NCHW fp32.
// x: [16,256,128,128] -> out: [16,256,129,129]
//
// Pure-streaming register kernel (copy-ubench shape): no LDS, no barriers.
// Thread = (img, out row r, col-group q): out cols [16q-2, 16q+14); q==7
// also emits cols 126..128. All 20 input float4 loads (4 window rows x 5)
// are independent and issued up-front -> ~320 B MLP per thread. Row pad is
// folded into zeroed weight rows (ws); col pad: the k==0 vector (cols
// 16q-8..16q-5... i.e. 16q-4..16q-1 window head) is load-skipped for q==0.
// a[k] = input col 16q-4+k for ALL q (fixes R8's q==0 shift bug).

__global__ __launch_bounds__(256) void blur_stream(
    const float* __restrict__ x,
    const float* __restrict__ kern,
    float* __restrict__ out)
{
    const int id  = blockIdx.x * 256 + threadIdx.x;   // 16512*256 = 4096*1032
    const int img = id / 1032;                        // 129 rows * 8 q
    const int rem = id - img * 1032;
    const int r   = rem >> 3;                         // 0..128
    const int q   = rem & 7;                          // 0..7

    const float* __restrict__ xi = x + (size_t)img * (128 * 128);

    // 4x4 weights (uniform -> SGPRs)
    float w[4][4];
#pragma unroll
    for (int p = 0; p < 4; ++p)
#pragma unroll
        for (int d = 0; d < 4; ++d)
            w[p][d] = kern[4 * p + d];

    // ---- issue all loads up-front (independent; max MLP) ----
    // A[p][k] = cols 16q-4+4k .. 16q-1+4k of window row p. For q==0 the
    // k==0 vector spans cols -4..-1 -> exec-masked off, zero-filled.
    float4 A[4][5];
#pragma unroll
    for (int p = 0; p < 4; ++p) {
        const int rr = r - 2 + p;
        const int rc = rr < 0 ? 0 : (rr > 127 ? 127 : rr);  // clamp = dummy
        const float* pr = xi + rc * 128 + 16 * q - 4;       // q==0: xi-4 (not
                                                            // deref'd at k=0)
        A[p][0] = q ? *(const float4*)pr : make_float4(0.f, 0.f, 0.f, 0.f);
#pragma unroll
        for (int k = 1; k < 5; ++k)
            A[p][k] = *(const float4*)(pr + 4 * k);
    }

    // row validity folded into weight copies (4 cndmask/row, no data mask)
    float ws[4][4];
#pragma unroll
    for (int p = 0; p < 4; ++p) {
        const bool ok = (unsigned)(r - 2 + p) < 128u;
#pragma unroll
        for (int d = 0; d < 4; ++d)
            ws[p][d] = ok ? w[p][d] : 0.0f;
    }

    // ---- compute: out col 16q-2+j uses in cols 16q-4+j..16q-1+j = a[j..j+3]
    float o[16];
#pragma unroll
    for (int j = 0; j < 16; ++j) o[j] = 0.0f;
    float e0 = 0.f, e1 = 0.f, e2 = 0.f;   // cols 126,127,128 (q==7 only)

#pragma unroll
    for (int p = 0; p < 4; ++p) {
        float a[20];
        a[0]  = A[p][0].x; a[1]  = A[p][0].y; a[2]  = A[p][0].z; a[3]  = A[p][0].w;
        a[4]  = A[p][1].x; a[5]  = A[p][1].y; a[6]  = A[p][1].z; a[7]  = A[p][1].w;
        a[8]  = A[p][2].x; a[9]  = A[p][2].y; a[10] = A[p][2].z; a[11] = A[p][2].w;
        a[12] = A[p][3].x; a[13] = A[p][3].y; a[14] = A[p][3].z; a[15] = A[p][3].w;
        a[16] = A[p][4].x; a[17] = A[p][4].y; a[18] = A[p][4].z; a[19] = A[p][4].w;
#pragma unroll
        for (int j = 0; j < 16; ++j) {
#pragma unroll
            for (int d = 0; d < 4; ++d)
                o[j] = fmaf(a[j + d], ws[p][d], o[j]);
        }
        // edge cols (q==7): a[16..19] = cols 124..127; in cols 128,129 = pad
        e0 = fmaf(a[16], ws[p][0], e0);
        e0 = fmaf(a[17], ws[p][1], e0);
        e0 = fmaf(a[18], ws[p][2], e0);
        e0 = fmaf(a[19], ws[p][3], e0);
        e1 = fmaf(a[17], ws[p][0], e1);
        e1 = fmaf(a[18], ws[p][1], e1);
        e1 = fmaf(a[19], ws[p][2], e1);
        e2 = fmaf(a[18], ws[p][0], e2);
        e2 = fmaf(a[19], ws[p][1], e2);
    }

    // ---- store ----
    float* po = out + (size_t)img * 16641 + (size_t)r * 129 + (16 * q - 2);
    if (q) { po[0] = o[0]; po[1] = o[1]; }   // cols 16q-2,16q-1 (q==0: pad)
#pragma unroll
    for (int j = 2; j < 16; ++j) po[j] = o[j];
    if (q == 7) { po[16] = e0; po[17] = e1; po[18] = e2; }  // cols 126..128
}

extern "C" void kernel_launch(void* const* d_in, const int* in_sizes, int n_in,
                              void* d_out, int out_size, void* d_ws, size_t ws_size,
                              hipStream_t stream) {
    const float* x    = (const float*)d_in[0];
    const float* kern = (const float*)d_in[1];
    float* out        = (float*)d_out;

    // 4096 images * 129 rows * 8 col-groups = 4,227,072 threads = 16512 * 256
    dim3 grid(16512), block(256);
    hipLaunchKernelGGL(blur_stream, grid, block, 0, stream, x, kern, out);
}

// Round 11
// 138.464 us; speedup vs baseline: 1.5044x; 1.5044x over previous
//
#include <hip/hip_runtime.h>

// Depthwise 4x4 FIR blur, pad (2,2)/(2,2), NCHW fp32.
// x: [16,256,128,128] -> out: [16,256,129,129]
//
// Persistent double-buffered kernel: 1024 blocks (4/CU resident) x 256 thr,
// each block processes 16 tiles (tile = 32 output rows = quarter image;
// s==3 tile also emits row 128). LDS = 2 slots x 36 input rows (18 KB) +
// zero-row. Per tile each wave issues L (5 or 4) 1KB global_load_lds;
// WAITV(L) keeps exactly the next tile's stage in flight across barriers
// (never vmcnt(0)); robust to store merging since L counts only own loads.
// Compute: thread = 4 cols (g) x 4 rows (c), xv ring via ds_read_b128,
// zero-row redirect for col pad, okr redirect for row pad, g==31 edge fold.

#define BAR() __builtin_amdgcn_s_barrier()
#define WAITV(NSTR) do {                                                     \
        asm volatile("s_waitcnt vmcnt(" NSTR ")" ::: "memory");              \
        __builtin_amdgcn_sched_barrier(0);                                   \
    } while (0)

__global__ __launch_bounds__(256) void blur_persist(
    const float* __restrict__ x,
    const float* __restrict__ kern,
    float* __restrict__ out)
{
    __shared__ __align__(16) float lds[2 * 36 * 128 + 128];  // slots + zrow

    const int tid  = threadIdx.x;
    const int wv   = tid >> 6;       // wave 0..3
    const int lane = tid & 63;
    const int c    = tid >> 5;       // row subchunk 0..7 (4 rows each)
    const int g    = tid & 31;       // col group: out cols 4g-2 .. 4g+1
    const bool lv  = (g >= 1);

    // XCD-contiguous tasks: 1024 blocks = 8 XCD x 128; block -> 16 tiles
    const int bid  = blockIdx.x;
    const int base = ((bid & 7) * 128 + (bid >> 3)) * 16;

    float w[4][4];
#pragma unroll
    for (int p = 0; p < 4; ++p)
#pragma unroll
        for (int d = 0; d < 4; ++d)
            w[p][d] = kern[4 * p + d];

    // zero-row (persistent, written once)
    if (tid < 128) lds[9216 + tid] = 0.0f;
    asm volatile("s_waitcnt lgkmcnt(0)" ::: "memory");
    const float* const zrow = &lds[9216];

    // ---- stage tile TT (input rows 32s-2 .. 32s+33 as 18 1KB pair-loads)
    // wave w: pairs w, w+4, w+8, w+12 (+ w+16 for w<2) -> L = 5/4 per wave.
#define STAGEPAIR(SB, XI, SS, PP) do {                                       \
        int rr_ = 32 * (SS) - 2 + 2 * (PP);                                  \
        rr_ = rr_ < 0 ? 0 : (rr_ > 126 ? 126 : rr_);   /* clamp = dummy */   \
        const float* src_ = (XI) + (size_t)rr_ * 128 + (lane << 2);          \
        const float* dst_ = (SB) + (PP) * 256;                               \
        __builtin_amdgcn_global_load_lds(                                    \
            (const __attribute__((address_space(1))) unsigned int*)src_,     \
            (__attribute__((address_space(3))) unsigned int*)dst_,           \
            16, 0, 0);                                                       \
    } while (0)

#define STAGE(TT) do {                                                       \
        const int t_ = (TT);                                                 \
        const int s_ = t_ & 3;                                               \
        const float* xi_ = x + (size_t)(t_ >> 2) * 16384;                    \
        float* sb_ = &lds[(t_ & 1) * 4608];                                  \
        STAGEPAIR(sb_, xi_, s_, wv + 0);                                     \
        STAGEPAIR(sb_, xi_, s_, wv + 4);                                     \
        STAGEPAIR(sb_, xi_, s_, wv + 8);                                     \
        STAGEPAIR(sb_, xi_, s_, wv + 12);                                    \
        if (wv < 2) STAGEPAIR(sb_, xi_, s_, wv + 16);                        \
    } while (0)

    // slot row k = input row 32s-2+k; out row 32s+4c+J window = k=4c+J..+3
#define LLOAD(S, KK) do {                                                    \
        const float* pb_ = sb + (4 * c + (KK)) * 128 + 4 * g;                \
        const bool okr_ = (unsigned)(32 * s_ - 2 + 4 * c + (KK)) < 128u;     \
        const float* pav_ = (okr_ && lv) ? (pb_ - 4) : zrow;                 \
        const float* pbv_ = okr_ ? pb_ : zrow;                               \
        float4 a_ = *(const float4*)pav_;                                    \
        float4 b_ = *(const float4*)pbv_;                                    \
        xv[S][0] = a_.x; xv[S][1] = a_.y; xv[S][2] = a_.z; xv[S][3] = a_.w;  \
        xv[S][4] = b_.x; xv[S][5] = b_.y; xv[S][6] = b_.z; xv[S][7] = b_.w;  \
    } while (0)

#define ACCP(S, P) do {                                                      \
        o0 = fmaf(xv[S][0], w[P][0], o0);                                    \
        o1 = fmaf(xv[S][1], w[P][0], o1);                                    \
        o2 = fmaf(xv[S][2], w[P][0], o2);                                    \
        o3 = fmaf(xv[S][3], w[P][0], o3);                                    \
        o0 = fmaf(xv[S][1], w[P][1], o0);                                    \
        o1 = fmaf(xv[S][2], w[P][1], o1);                                    \
        o2 = fmaf(xv[S][3], w[P][1], o2);                                    \
        o3 = fmaf(xv[S][4], w[P][1], o3);                                    \
        o0 = fmaf(xv[S][2], w[P][2], o0);                                    \
        o1 = fmaf(xv[S][3], w[P][2], o1);                                    \
        o2 = fmaf(xv[S][4], w[P][2], o2);                                    \
        o3 = fmaf(xv[S][5], w[P][2], o3);                                    \
        o0 = fmaf(xv[S][3], w[P][3], o0);                                    \
        o1 = fmaf(xv[S][4], w[P][3], o1);                                    \
        o2 = fmaf(xv[S][5], w[P][3], o2);                                    \
        o3 = fmaf(xv[S][6], w[P][3], o3);                                    \
    } while (0)

#define XROW(S, P) do {                                                      \
        e0 = fmaf(xv[S][4], w[P][0], e0);                                    \
        e0 = fmaf(xv[S][5], w[P][1], e0);                                    \
        e0 = fmaf(xv[S][6], w[P][2], e0);                                    \
        e0 = fmaf(xv[S][7], w[P][3], e0);                                    \
        e1 = fmaf(xv[S][5], w[P][0], e1);                                    \
        e1 = fmaf(xv[S][6], w[P][1], e1);                                    \
        e1 = fmaf(xv[S][7], w[P][2], e1);                                    \
        e2 = fmaf(xv[S][6], w[P][0], e2);                                    \
        e2 = fmaf(xv[S][7], w[P][1], e2);                                    \
    } while (0)

#define CS(SA, SB_, SC, SD, PO) do {                                         \
        float o0 = 0.f, o1 = 0.f, o2 = 0.f, o3 = 0.f;                        \
        ACCP(SA, 0); ACCP(SB_, 1); ACCP(SC, 2); ACCP(SD, 3);                 \
        if (lv) { (PO)[0] = o0; (PO)[1] = o1; }                              \
        (PO)[2] = o2;                                                        \
        (PO)[3] = o3;                                                        \
        if (g == 31) {                                                       \
            float e0 = 0.f, e1 = 0.f, e2 = 0.f;                              \
            XROW(SA, 0); XROW(SB_, 1); XROW(SC, 2); XROW(SD, 3);             \
            (PO)[4] = e0; (PO)[5] = e1; (PO)[6] = e2;  /* cols 126..128 */   \
        }                                                                    \
    } while (0)

#define COMPUTE(TT) do {                                                     \
        const int t_ = (TT);                                                 \
        const int s_ = t_ & 3;                                               \
        const float* sb = &lds[(t_ & 1) * 4608];                             \
        float* oi_ = out + (size_t)(t_ >> 2) * 16641;                        \
        float xv[4][8];                                                      \
        float* po = oi_ + (size_t)(32 * s_ + 4 * c) * 129 + 4 * g - 2;       \
        LLOAD(0, 0); LLOAD(1, 1); LLOAD(2, 2); LLOAD(3, 3);                  \
        CS(0, 1, 2, 3, po); LLOAD(0, 4); po += 129;                          \
        CS(1, 2, 3, 0, po); LLOAD(1, 5); po += 129;                          \
        CS(2, 3, 0, 1, po); LLOAD(2, 6); po += 129;                          \
        CS(3, 0, 1, 2, po); po += 129;                                       \
        if (s_ == 3 && c == 7) {         /* out row 128: k=32..35 */         \
            LLOAD(3, 7);                                                     \
            CS(0, 1, 2, 3, po);                                              \
        }                                                                    \
    } while (0)

    // ---- persistent pipeline over 16 tiles, 2-slot double buffer ----
    STAGE(base + 0);
    STAGE(base + 1);
    for (int i = 0; i < 16; ++i) {
        // drain everything older than the NEXT tile's stage; keep it in
        // flight. Own-load count only -> robust to store vectorization.
        if (wv < 2) WAITV("5"); else WAITV("4");
        BAR();
        COMPUTE(base + i);
        BAR();
        if (i < 14) STAGE(base + i + 2);
    }

#undef STAGEPAIR
#undef STAGE
#undef LLOAD
#undef ACCP
#undef XROW
#undef CS
#undef COMPUTE
}

extern "C" void kernel_launch(void* const* d_in, const int* in_sizes, int n_in,
                              void* d_out, int out_size, void* d_ws, size_t ws_size,
                              hipStream_t stream) {
    const float* x    = (const float*)d_in[0];
    const float* kern = (const float*)d_in[1];
    float* out        = (float*)d_out;

    // 1024 persistent blocks (4/CU) x 16 tiles = 16384 tiles
    // = 4096 images x 4 quarter-image tiles
    dim3 grid(1024), block(256);
    hipLaunchKernelGGL(blur_persist, grid, block, 0, stream, x, kern, out);
}